// Round 2
// baseline (143.656 us; speedup 1.0000x reference)
//
#include <hip/hip_runtime.h>
#include <hip/hip_bf16.h>

#define Bsz 16
#define Nn  1024
#define Ff  256
#define ALPHA 0.2f
#define NEG_BIG -9.0e15f
#define LOG2E 1.44269504f

typedef __attribute__((ext_vector_type(8))) short short8;
typedef __attribute__((ext_vector_type(4))) float f32x4;
typedef __attribute__((ext_vector_type(4))) unsigned short ushort4_t;

__device__ __forceinline__ unsigned short f2bf(float x) {
    union { __hip_bfloat16 b; unsigned short u; } cv;
    cv.b = __float2bfloat16(x);
    return cv.u;
}

__device__ __forceinline__ float exp2_fast(float x) {
#if __has_builtin(__builtin_amdgcn_exp2f)
    return __builtin_amdgcn_exp2f(x);
#else
    return exp2f(x);
#endif
}

__device__ __forceinline__ float rcp_fast(float x) {
#if __has_builtin(__builtin_amdgcn_rcpf)
    return __builtin_amdgcn_rcpf(x);
#else
    return 1.f / x;
#endif
}

// ---- K0: w1 = W@a1 ; w2 = W@a2  (64 blocks, wave per output f) ------------
__global__ __launch_bounds__(256) void gat_prep(
    const float* __restrict__ W, const float* __restrict__ a,
    float* __restrict__ w1, float* __restrict__ w2)
{
    const int t = threadIdx.x, w = t >> 6, ln = t & 63;
    __shared__ float a1s[Ff], a2s[Ff];
    a1s[t] = a[t];
    a2s[t] = a[Ff + t];
    __syncthreads();
    const int f = blockIdx.x * 4 + w;
    float s1 = 0.f, s2 = 0.f;
    #pragma unroll
    for (int c = 0; c < 4; c++) {
        const int o = ln + 64 * c;
        const float wv = W[(size_t)f * Ff + o];
        s1 += wv * a1s[o];
        s2 += wv * a2s[o];
    }
    #pragma unroll
    for (int off = 1; off < 64; off <<= 1) {
        s1 += __shfl_xor(s1, off, 64);
        s2 += __shfl_xor(s2, off, 64);
    }
    if (ln == 0) { w1[f] = s1; w2[f] = s2; }
}

// ---- K1: pack/transpose h,W to bf16 K-tiles + fused f1/f2 -----------------
__global__ __launch_bounds__(256) void pack_f(
    const float* __restrict__ h, const float* __restrict__ W,
    const float* __restrict__ w1, const float* __restrict__ w2,
    unsigned short* __restrict__ hK, unsigned short* __restrict__ WK,
    float* __restrict__ f1, float* __restrict__ f2)
{
    __shared__ __align__(16) float tile[32][260];
    const int id = blockIdx.x, t = threadIdx.x, w = t >> 6, ln = t & 63;
    const bool isH = (id < 512);
    const float* src;
    unsigned short* dst;
    int grow0 = 0;
    if (isH) {
        const int b = id >> 5, kt = id & 31;
        grow0 = b * Nn + kt * 32;
        src = h + (size_t)grow0 * Ff;
        dst = hK + ((size_t)(b * 32 + kt)) * 8192;
    } else {
        const int ft = id - 512;
        src = W + (size_t)ft * 32 * Ff;
        dst = WK + (size_t)ft * 8192;
    }
    #pragma unroll
    for (int rr = 0; rr < 8; rr++) {
        const int row = rr * 4 + w;
        const int col = ln * 4;
        *(float4*)&tile[row][col] = *(const float4*)&src[row * Ff + col];
    }
    __syncthreads();

    unsigned* d32 = (unsigned*)dst;
    #pragma unroll
    for (int k = 0; k < 16; k++) {
        const int fidx = k * 256 + t;
        const int o = fidx >> 4, q = fidx & 15;
        const unsigned lo = f2bf(tile[2 * q][o]);
        const unsigned hi = f2bf(tile[2 * q + 1][o]);
        d32[fidx] = lo | (hi << 16);
    }

    if (isH) {
        float w1r[4], w2r[4];
        #pragma unroll
        for (int c = 0; c < 4; c++) {
            w1r[c] = w1[ln + 64 * c];
            w2r[c] = w2[ln + 64 * c];
        }
        #pragma unroll
        for (int rr = 0; rr < 8; rr++) {
            const int row = rr * 4 + w;
            float s1 = 0.f, s2 = 0.f;
            #pragma unroll
            for (int c = 0; c < 4; c++) {
                const float hv = tile[row][ln + 64 * c];
                s1 += hv * w1r[c];
                s2 += hv * w2r[c];
            }
            #pragma unroll
            for (int off = 1; off < 64; off <<= 1) {
                s1 += __shfl_xor(s1, off, 64);
                s2 += __shfl_xor(s2, off, 64);
            }
            if (ln == 0) { f1[grow0 + row] = s1; f2[grow0 + row] = s2; }
        }
    }
}

// ---- K2: softmax -> G = P@h (MFMA) -> out = elu(G@W) (MFMA), TI=32 --------
// Phase A is single-pass: max_j lrelu(f1+f2[j]) == lrelu(f1 + max_j f2[j])
// (lrelu monotone), so the row softmax shift comes from ONE per-wave f2-max
// (hidden under the adj HBM loads). Elements are exp2'd, masked to 0, packed
// bf16 and stored immediately (no e[] arrays). P is written UNNORMALIZED;
// row sums go to ss[32] and the 1/s scale is applied to the phase-B
// accumulator (rows quad*4+reg align with ss layout exactly).
#define TI 32
__global__ __launch_bounds__(1024, 8) void gat_attn(
    const int* __restrict__ adj,
    const float* __restrict__ f1, const float* __restrict__ f2,
    const unsigned short* __restrict__ hK, const unsigned short* __restrict__ WK,
    float* __restrict__ out)
{
    // 64 KB: P (swizzled, stride 1024) in phases A/B; G (stride 264) in C
    __shared__ __align__(16) unsigned short pbf[TI * 1024];
    __shared__ __align__(16) float ss[TI];
    const int t = threadIdx.x, w = t >> 6, ln = t & 63;   // 16 waves
    const int m = ln & 15, quad = ln >> 4;
    const int bid = blockIdx.x;
    const int b  = 2 * (bid & 7) + ((bid >> 3) & 1);      // XCD-local batches
    const int i0 = (bid >> 4) * TI;

    // ---- Phase A: wave w owns rows 2w, 2w+1 ----
    const int r0 = 2 * w, r1 = r0 + 1;
    const int grb = b * Nn + i0 + r0;
    const int* aptr = adj + (size_t)grb * Nn;
    int4 av0[4], av1[4];
    #pragma unroll
    for (int c = 0; c < 4; c++) {
        av0[c] = *(const int4*)&aptr[c * 256 + 4 * ln];
        av1[c] = *(const int4*)&aptr[Nn + c * 256 + 4 * ln];
    }

    float4 f2r[4];
    #pragma unroll
    for (int c = 0; c < 4; c++)
        f2r[c] = *(const float4*)&f2[b * Nn + 256 * c + 4 * ln];

    // per-wave max of the f2 row (reduction overlaps the adj loads)
    float mx2 = fmaxf(fmaxf(f2r[0].x, f2r[0].y), fmaxf(f2r[0].z, f2r[0].w));
    #pragma unroll
    for (int c = 1; c < 4; c++)
        mx2 = fmaxf(mx2, fmaxf(fmaxf(f2r[c].x, f2r[c].y), fmaxf(f2r[c].z, f2r[c].w)));
    #pragma unroll
    for (int off = 1; off < 64; off <<= 1)
        mx2 = fmaxf(mx2, __shfl_xor(mx2, off, 64));

    // pre-scale f2 by log2(e): lrelu commutes with positive scaling
    #pragma unroll
    for (int c = 0; c < 4; c++) {
        f2r[c].x *= LOG2E; f2r[c].y *= LOG2E;
        f2r[c].z *= LOG2E; f2r[c].w *= LOG2E;
    }

    const float fi0 = f1[grb], fi1 = f1[grb + 1];
    float q0 = fi0 + mx2; q0 = fmaxf(q0, ALPHA * q0);
    float q1 = fi1 + mx2; q1 = fmaxf(q1, ALPHA * q1);
    const float mx0L = q0 * LOG2E, mx1L = q1 * LOG2E;
    const float fi0L = fi0 * LOG2E, fi1L = fi1 * LOG2E;
    const int sw0 = (r0 & 7) << 3, sw1 = (r1 & 7) << 3;

    float s0 = 0.f, s1 = 0.f;
    #pragma unroll
    for (int c = 0; c < 4; c++) {
        const float4 fv = f2r[c];
        float x, p00, p01, p02, p03, p10, p11, p12, p13;
        x = fi0L + fv.x; x = fmaxf(x, ALPHA * x); p00 = exp2_fast(x - mx0L); p00 = av0[c].x > 0 ? p00 : 0.f;
        x = fi0L + fv.y; x = fmaxf(x, ALPHA * x); p01 = exp2_fast(x - mx0L); p01 = av0[c].y > 0 ? p01 : 0.f;
        x = fi0L + fv.z; x = fmaxf(x, ALPHA * x); p02 = exp2_fast(x - mx0L); p02 = av0[c].z > 0 ? p02 : 0.f;
        x = fi0L + fv.w; x = fmaxf(x, ALPHA * x); p03 = exp2_fast(x - mx0L); p03 = av0[c].w > 0 ? p03 : 0.f;
        x = fi1L + fv.x; x = fmaxf(x, ALPHA * x); p10 = exp2_fast(x - mx1L); p10 = av1[c].x > 0 ? p10 : 0.f;
        x = fi1L + fv.y; x = fmaxf(x, ALPHA * x); p11 = exp2_fast(x - mx1L); p11 = av1[c].y > 0 ? p11 : 0.f;
        x = fi1L + fv.z; x = fmaxf(x, ALPHA * x); p12 = exp2_fast(x - mx1L); p12 = av1[c].z > 0 ? p12 : 0.f;
        x = fi1L + fv.w; x = fmaxf(x, ALPHA * x); p13 = exp2_fast(x - mx1L); p13 = av1[c].w > 0 ? p13 : 0.f;
        s0 += (p00 + p01) + (p02 + p03);
        s1 += (p10 + p11) + (p12 + p13);
        const int j = 256 * c + 4 * ln;
        ushort4_t v0 = { f2bf(p00), f2bf(p01), f2bf(p02), f2bf(p03) };
        ushort4_t v1 = { f2bf(p10), f2bf(p11), f2bf(p12), f2bf(p13) };
        *(ushort4_t*)&pbf[r0 * 1024 + (j ^ sw0)] = v0;
        *(ushort4_t*)&pbf[r1 * 1024 + (j ^ sw1)] = v1;
    }
    #pragma unroll
    for (int off = 1; off < 64; off <<= 1) {
        s0 += __shfl_xor(s0, off, 64);
        s1 += __shfl_xor(s1, off, 64);
    }
    if (ln == 0) { ss[r0] = s0; ss[r1] = s1; }
    __syncthreads();

    // ---- Phase B: G = softmax(P) @ h_b ; wave n-slice 16, both m-halves ----
    const int n0 = w * 16;
    const unsigned short* hKb = hK + (size_t)b * 32 * 8192;
    const int arow0 = m * 1024, arow1 = (16 + m) * 1024;
    const int asw = (m & 7) << 3;
    #define AF0(kt) (*(const short8*)&pbf[arow0 + ((((kt) * 32) + quad * 8) ^ asw)])
    #define AF1(kt) (*(const short8*)&pbf[arow1 + ((((kt) * 32) + quad * 8) ^ asw)])
    #define BF(kt)  (*(const short8*)&hKb[(size_t)(kt) * 8192 + (n0 + m) * 32 + quad * 8])

    f32x4 acc0 = {0.f,0.f,0.f,0.f}, acc1 = acc0;
    short8 a0c = AF0(0), a1c = AF1(0);
    short8 bc = BF(0), bn = BF(1);
    #pragma unroll
    for (int kt = 0; kt < 32; kt++) {
        short8 bnn = bc, a0n = a0c, a1n = a1c;
        if (kt + 2 < 32) bnn = BF(kt + 2);
        if (kt + 1 < 32) { a0n = AF0(kt + 1); a1n = AF1(kt + 1); }
        acc0 = __builtin_amdgcn_mfma_f32_16x16x32_bf16(a0c, bc, acc0, 0, 0, 0);
        acc1 = __builtin_amdgcn_mfma_f32_16x16x32_bf16(a1c, bc, acc1, 0, 0, 0);
        a0c = a0n; a1c = a1n; bc = bn; bn = bnn;
    }

    // normalize rows by 1/s (C row = quad*4+reg aligns with ss layout)
    const f32x4 sv0 = *(const f32x4*)&ss[quad * 4];
    const f32x4 sv1 = *(const f32x4*)&ss[16 + quad * 4];

    __syncthreads();   // P dead; reuse pbf for G (stride 264)
    #pragma unroll
    for (int reg = 0; reg < 4; reg++) {
        const float i0s = rcp_fast(fmaxf(sv0[reg], 1e-30f));
        const float i1s = rcp_fast(fmaxf(sv1[reg], 1e-30f));
        pbf[(quad * 4 + reg) * 264 + n0 + m]      = f2bf(acc0[reg] * i0s);
        pbf[(16 + quad * 4 + reg) * 264 + n0 + m] = f2bf(acc1[reg] * i1s);
    }
    __syncthreads();

    // ---- Phase C: out = elu( G @ W ) ; same wave mapping ----
    #define GA0(kt) (*(const short8*)&pbf[m * 264 + (kt) * 32 + quad * 8])
    #define GA1(kt) (*(const short8*)&pbf[(16 + m) * 264 + (kt) * 32 + quad * 8])
    #define WB(kt)  (*(const short8*)&WK[(size_t)(kt) * 8192 + (n0 + m) * 32 + quad * 8])

    f32x4 c0 = {0.f,0.f,0.f,0.f}, c1 = c0;
    short8 ga0 = GA0(0), ga1 = GA1(0), wb = WB(0);
    #pragma unroll
    for (int kt = 0; kt < 8; kt++) {
        short8 ga0n = ga0, ga1n = ga1, wbn = wb;
        if (kt + 1 < 8) { ga0n = GA0(kt + 1); ga1n = GA1(kt + 1); wbn = WB(kt + 1); }
        c0 = __builtin_amdgcn_mfma_f32_16x16x32_bf16(ga0, wb, c0, 0, 0, 0);
        c1 = __builtin_amdgcn_mfma_f32_16x16x32_bf16(ga1, wb, c1, 0, 0, 0);
        ga0 = ga0n; ga1 = ga1n; wb = wbn;
    }
    const size_t ob = (size_t)(b * Nn) + i0;
    #pragma unroll
    for (int reg = 0; reg < 4; reg++) {
        float v;
        v = c0[reg]; v = v > 0.f ? v : (__expf(v) - 1.f);
        out[(ob + quad * 4 + reg) * Ff + n0 + m] = v;
        v = c1[reg]; v = v > 0.f ? v : (__expf(v) - 1.f);
        out[(ob + 16 + quad * 4 + reg) * Ff + n0 + m] = v;
    }
}

extern "C" void kernel_launch(void* const* d_in, const int* in_sizes, int n_in,
                              void* d_out, int out_size, void* d_ws, size_t ws_size,
                              hipStream_t stream)
{
    const void* h   = d_in[0];
    const void* adj = d_in[1];
    const void* W   = d_in[2];
    const void* a   = d_in[3];
    for (int i = 0; i < n_in; i++) {
        if      (in_sizes[i] == Bsz * Nn * Ff) h   = d_in[i];
        else if (in_sizes[i] == Bsz * Nn * Nn) adj = d_in[i];
        else if (in_sizes[i] == Ff * Ff)       W   = d_in[i];
        else if (in_sizes[i] == 2 * Ff)        a   = d_in[i];
    }
    float* out = (float*)d_out;

    char*  wsb = (char*)d_ws;
    float* w1  = (float*)wsb;                                   // 1 KiB
    float* w2  = w1 + Ff;                                       // 1 KiB
    float* f1  = (float*)(wsb + 4096);                          // 64 KiB
    float* f2  = f1 + Bsz * Nn;                                 // 64 KiB
    unsigned short* hK = (unsigned short*)(wsb + 4096 + 2 * 65536);  // 8 MiB
    unsigned short* WK = hK + (size_t)Bsz * 32 * 8192;               // 128 KiB

    gat_prep<<<64, 256, 0, stream>>>((const float*)W, (const float*)a, w1, w2);
    pack_f<<<520, 256, 0, stream>>>((const float*)h, (const float*)W, w1, w2, hK, WK, f1, f2);
    gat_attn<<<Bsz * (Nn / TI), 1024, 0, stream>>>((const int*)adj, f1, f2, hK, WK, out);
}

// Round 4
// 143.008 us; speedup vs baseline: 1.0045x; 1.0045x over previous
//
#include <hip/hip_runtime.h>
#include <hip/hip_bf16.h>

#define Bsz 16
#define Nn  1024
#define Ff  256
#define ALPHA 0.2f
#define LOG2E 1.44269504f

typedef __attribute__((ext_vector_type(8))) short short8;
typedef __attribute__((ext_vector_type(4))) float f32x4;
typedef __attribute__((ext_vector_type(4))) unsigned short ushort4_t;

__device__ __forceinline__ unsigned short f2bf(float x) {
    union { __hip_bfloat16 b; unsigned short u; } cv;
    cv.b = __float2bfloat16(x);
    return cv.u;
}

__device__ __forceinline__ float exp2_fast(float x) {
#if __has_builtin(__builtin_amdgcn_exp2f)
    return __builtin_amdgcn_exp2f(x);
#else
    return exp2f(x);
#endif
}

__device__ __forceinline__ float rcp_fast(float x) {
#if __has_builtin(__builtin_amdgcn_rcpf)
    return __builtin_amdgcn_rcpf(x);
#else
    return 1.f / x;
#endif
}

// uniformize a wave-uniform u64 into SGPRs
__device__ __forceinline__ unsigned long long rfl64(unsigned long long v) {
    unsigned lo = __builtin_amdgcn_readfirstlane((unsigned)v);
    unsigned hi = __builtin_amdgcn_readfirstlane((unsigned)(v >> 32));
    return ((unsigned long long)hi << 32) | lo;
}

// p if (bit `lane` of uniform mask ms) else 0
__device__ __forceinline__ float maskf(float p, unsigned long long ms, int ln) {
#if __has_builtin(__builtin_amdgcn_inverse_ballot_w64)
    return __builtin_amdgcn_inverse_ballot_w64(ms) ? p : 0.f;
#else
    return ((ms >> ln) & 1ull) ? p : 0.f;
#endif
}

// ---- K0: fused {w1/w2 prep} + {adj -> ballot bitmask} ---------------------
// blocks 0..63: w1 = W@a1, w2 = W@a2 (wave per output f)
// blocks 64..2111: pack adj (64 MB int32) into abit (2 MB): per row, per
// 256-col block c, 4 u64 ballots; bit ln of mask k = adj[row][256c+4*ln+k] —
// exactly the lane layout gat_attn's phase A consumes.
__global__ __launch_bounds__(256) void prep_pack(
    const float* __restrict__ W, const float* __restrict__ a,
    const int* __restrict__ adj,
    float* __restrict__ w1, float* __restrict__ w2,
    unsigned long long* __restrict__ abit)
{
    const int t = threadIdx.x, w = t >> 6, ln = t & 63;
    __shared__ float a1s[Ff], a2s[Ff];
    if (blockIdx.x < 64) {
        a1s[t] = a[t];
        a2s[t] = a[Ff + t];
        __syncthreads();
        const int f = blockIdx.x * 4 + w;
        float s1 = 0.f, s2 = 0.f;
        #pragma unroll
        for (int c = 0; c < 4; c++) {
            const int o = ln + 64 * c;
            const float wv = W[(size_t)f * Ff + o];
            s1 += wv * a1s[o];
            s2 += wv * a2s[o];
        }
        #pragma unroll
        for (int off = 1; off < 64; off <<= 1) {
            s1 += __shfl_xor(s1, off, 64);
            s2 += __shfl_xor(s2, off, 64);
        }
        if (ln == 0) { w1[f] = s1; w2[f] = s2; }
        return;
    }
    // adj pack: wave w handles rows id2*8 + 2w, +1
    const int id2 = blockIdx.x - 64;            // 0..2047
    const int row0 = id2 * 8 + 2 * w;
    const int* ap = adj + (size_t)row0 * Nn;
    int4 vv[8];                                  // all 8 loads in flight
    #pragma unroll
    for (int u = 0; u < 8; u++)
        vv[u] = *(const int4*)&ap[(u >> 2) * Nn + (u & 3) * 256 + 4 * ln];
    #pragma unroll
    for (int u = 0; u < 8; u++) {
        const unsigned long long b0 = __ballot(vv[u].x > 0);
        const unsigned long long b1 = __ballot(vv[u].y > 0);
        const unsigned long long b2 = __ballot(vv[u].z > 0);
        const unsigned long long b3 = __ballot(vv[u].w > 0);
        if (ln == 0) {
            const size_t base = (size_t)(row0 + (u >> 2)) * 16 + (u & 3) * 4;
            abit[base]     = b0;
            abit[base + 1] = b1;
            abit[base + 2] = b2;
            abit[base + 3] = b3;
        }
    }
}

// ---- K1: pack/transpose h,W to bf16 K-tiles + fused f1/f2 -----------------
__global__ __launch_bounds__(256) void pack_f(
    const float* __restrict__ h, const float* __restrict__ W,
    const float* __restrict__ w1, const float* __restrict__ w2,
    unsigned short* __restrict__ hK, unsigned short* __restrict__ WK,
    float* __restrict__ f1, float* __restrict__ f2)
{
    __shared__ __align__(16) float tile[32][260];
    const int id = blockIdx.x, t = threadIdx.x, w = t >> 6, ln = t & 63;
    const bool isH = (id < 512);
    const float* src;
    unsigned short* dst;
    int grow0 = 0;
    if (isH) {
        const int b = id >> 5, kt = id & 31;
        grow0 = b * Nn + kt * 32;
        src = h + (size_t)grow0 * Ff;
        dst = hK + ((size_t)(b * 32 + kt)) * 8192;
    } else {
        const int ft = id - 512;
        src = W + (size_t)ft * 32 * Ff;
        dst = WK + (size_t)ft * 8192;
    }
    #pragma unroll
    for (int rr = 0; rr < 8; rr++) {
        const int row = rr * 4 + w;
        const int col = ln * 4;
        *(float4*)&tile[row][col] = *(const float4*)&src[row * Ff + col];
    }
    __syncthreads();

    unsigned* d32 = (unsigned*)dst;
    #pragma unroll
    for (int k = 0; k < 16; k++) {
        const int fidx = k * 256 + t;
        const int o = fidx >> 4, q = fidx & 15;
        const unsigned lo = f2bf(tile[2 * q][o]);
        const unsigned hi = f2bf(tile[2 * q + 1][o]);
        d32[fidx] = lo | (hi << 16);
    }

    if (isH) {
        float w1r[4], w2r[4];
        #pragma unroll
        for (int c = 0; c < 4; c++) {
            w1r[c] = w1[ln + 64 * c];
            w2r[c] = w2[ln + 64 * c];
        }
        #pragma unroll
        for (int rr = 0; rr < 8; rr++) {
            const int row = rr * 4 + w;
            float s1 = 0.f, s2 = 0.f;
            #pragma unroll
            for (int c = 0; c < 4; c++) {
                const float hv = tile[row][ln + 64 * c];
                s1 += hv * w1r[c];
                s2 += hv * w2r[c];
            }
            #pragma unroll
            for (int off = 1; off < 64; off <<= 1) {
                s1 += __shfl_xor(s1, off, 64);
                s2 += __shfl_xor(s2, off, 64);
            }
            if (ln == 0) { f1[grow0 + row] = s1; f2[grow0 + row] = s2; }
        }
    }
}

// ---- K2: softmax -> G = P@h (MFMA) -> out = elu(G@W) (MFMA), TI=32 --------
// adj arrives as 2 MB of ballot bitmasks (L2-resident broadcast reads) —
// removes the 64 MB HBM stream that bound rounds 0-2 at ~1.5 TB/s.
#define TI 32
__global__ __launch_bounds__(1024, 8) void gat_attn(
    const unsigned long long* __restrict__ abit,
    const float* __restrict__ f1, const float* __restrict__ f2,
    const unsigned short* __restrict__ hK, const unsigned short* __restrict__ WK,
    float* __restrict__ out)
{
    // 64 KB: P (swizzled, stride 1024) in phases A/B; G (stride 264) in C
    __shared__ __align__(16) unsigned short pbf[TI * 1024];
    __shared__ __align__(16) float ss[TI];
    const int t = threadIdx.x, w = t >> 6, ln = t & 63;   // 16 waves
    const int m = ln & 15, quad = ln >> 4;
    const int bid = blockIdx.x;
    const int b  = 2 * (bid & 7) + ((bid >> 3) & 1);      // XCD-local batches
    const int i0 = (bid >> 4) * TI;

    // ---- Phase A: wave w owns rows 2w, 2w+1 ----
    const int r0 = 2 * w, r1 = r0 + 1;
    const int grb = b * Nn + i0 + r0;
    const unsigned long long* ab = abit + (size_t)grb * 16;  // rows r0,r1: 32 u64

    float4 f2r[4];
    #pragma unroll
    for (int c = 0; c < 4; c++)
        f2r[c] = *(const float4*)&f2[b * Nn + 256 * c + 4 * ln];

    // per-wave max of the f2 row (valid shift: lrelu is monotone)
    float mx2 = fmaxf(fmaxf(f2r[0].x, f2r[0].y), fmaxf(f2r[0].z, f2r[0].w));
    #pragma unroll
    for (int c = 1; c < 4; c++)
        mx2 = fmaxf(mx2, fmaxf(fmaxf(f2r[c].x, f2r[c].y), fmaxf(f2r[c].z, f2r[c].w)));
    #pragma unroll
    for (int off = 1; off < 64; off <<= 1)
        mx2 = fmaxf(mx2, __shfl_xor(mx2, off, 64));

    #pragma unroll
    for (int c = 0; c < 4; c++) {
        f2r[c].x *= LOG2E; f2r[c].y *= LOG2E;
        f2r[c].z *= LOG2E; f2r[c].w *= LOG2E;
    }

    const float fi0 = f1[grb], fi1 = f1[grb + 1];
    float q0 = fi0 + mx2; q0 = fmaxf(q0, ALPHA * q0);
    float q1 = fi1 + mx2; q1 = fmaxf(q1, ALPHA * q1);
    const float mx0L = q0 * LOG2E, mx1L = q1 * LOG2E;
    const float fi0L = fi0 * LOG2E, fi1L = fi1 * LOG2E;
    const int sw0 = (r0 & 7) << 3, sw1 = (r1 & 7) << 3;

    // software-pipelined mask loads: current-c in SGPRs, next-c in flight
    ulonglong2 qa0 = *(const ulonglong2*)&ab[0];
    ulonglong2 qb0 = *(const ulonglong2*)&ab[2];
    ulonglong2 qc0 = *(const ulonglong2*)&ab[16];
    ulonglong2 qd0 = *(const ulonglong2*)&ab[18];

    float s0 = 0.f, s1 = 0.f;
    #pragma unroll
    for (int c = 0; c < 4; c++) {
        ulonglong2 qa1 = qa0, qb1 = qb0, qc1 = qc0, qd1 = qd0;
        if (c < 3) {
            qa1 = *(const ulonglong2*)&ab[4 * (c + 1)];
            qb1 = *(const ulonglong2*)&ab[4 * (c + 1) + 2];
            qc1 = *(const ulonglong2*)&ab[16 + 4 * (c + 1)];
            qd1 = *(const ulonglong2*)&ab[16 + 4 * (c + 1) + 2];
        }
        const unsigned long long m00 = rfl64(qa0.x), m01 = rfl64(qa0.y);
        const unsigned long long m02 = rfl64(qb0.x), m03 = rfl64(qb0.y);
        const unsigned long long m10 = rfl64(qc0.x), m11 = rfl64(qc0.y);
        const unsigned long long m12 = rfl64(qd0.x), m13 = rfl64(qd0.y);
        const float4 fv = f2r[c];
        float x, p00, p01, p02, p03, p10, p11, p12, p13;
        x = fi0L + fv.x; x = fmaxf(x, ALPHA * x); p00 = maskf(exp2_fast(x - mx0L), m00, ln);
        x = fi0L + fv.y; x = fmaxf(x, ALPHA * x); p01 = maskf(exp2_fast(x - mx0L), m01, ln);
        x = fi0L + fv.z; x = fmaxf(x, ALPHA * x); p02 = maskf(exp2_fast(x - mx0L), m02, ln);
        x = fi0L + fv.w; x = fmaxf(x, ALPHA * x); p03 = maskf(exp2_fast(x - mx0L), m03, ln);
        x = fi1L + fv.x; x = fmaxf(x, ALPHA * x); p10 = maskf(exp2_fast(x - mx1L), m10, ln);
        x = fi1L + fv.y; x = fmaxf(x, ALPHA * x); p11 = maskf(exp2_fast(x - mx1L), m11, ln);
        x = fi1L + fv.z; x = fmaxf(x, ALPHA * x); p12 = maskf(exp2_fast(x - mx1L), m12, ln);
        x = fi1L + fv.w; x = fmaxf(x, ALPHA * x); p13 = maskf(exp2_fast(x - mx1L), m13, ln);
        s0 += (p00 + p01) + (p02 + p03);
        s1 += (p10 + p11) + (p12 + p13);
        const int j = 256 * c + 4 * ln;
        ushort4_t v0 = { f2bf(p00), f2bf(p01), f2bf(p02), f2bf(p03) };
        ushort4_t v1 = { f2bf(p10), f2bf(p11), f2bf(p12), f2bf(p13) };
        *(ushort4_t*)&pbf[r0 * 1024 + (j ^ sw0)] = v0;
        *(ushort4_t*)&pbf[r1 * 1024 + (j ^ sw1)] = v1;
        qa0 = qa1; qb0 = qb1; qc0 = qc1; qd0 = qd1;
    }
    #pragma unroll
    for (int off = 1; off < 64; off <<= 1) {
        s0 += __shfl_xor(s0, off, 64);
        s1 += __shfl_xor(s1, off, 64);
    }
    if (ln == 0) { ss[r0] = s0; ss[r1] = s1; }

    // ---- Phase B: G = softmax(P) @ h_b ; wave n-slice 16, both m-halves ----
    const int n0 = w * 16;
    const unsigned short* hKb = hK + (size_t)b * 32 * 8192;
    const int arow0 = m * 1024, arow1 = (16 + m) * 1024;
    const int asw = (m & 7) << 3;
    #define AF0(kt) (*(const short8*)&pbf[arow0 + ((((kt) * 32) + quad * 8) ^ asw)])
    #define AF1(kt) (*(const short8*)&pbf[arow1 + ((((kt) * 32) + quad * 8) ^ asw)])
    #define BF(kt)  (*(const short8*)&hKb[(size_t)(kt) * 8192 + (n0 + m) * 32 + quad * 8])

    // prefetch B-frags (no pbf dependency) before the barrier
    short8 bc = BF(0), bn = BF(1);
    __syncthreads();

    f32x4 acc0 = {0.f,0.f,0.f,0.f}, acc1 = acc0;
    short8 a0c = AF0(0), a1c = AF1(0);
    __builtin_amdgcn_s_setprio(1);
    #pragma unroll
    for (int kt = 0; kt < 32; kt++) {
        short8 bnn = bc, a0n = a0c, a1n = a1c;
        if (kt + 2 < 32) bnn = BF(kt + 2);
        if (kt + 1 < 32) { a0n = AF0(kt + 1); a1n = AF1(kt + 1); }
        acc0 = __builtin_amdgcn_mfma_f32_16x16x32_bf16(a0c, bc, acc0, 0, 0, 0);
        acc1 = __builtin_amdgcn_mfma_f32_16x16x32_bf16(a1c, bc, acc1, 0, 0, 0);
        a0c = a0n; a1c = a1n; bc = bn; bn = bnn;
    }
    __builtin_amdgcn_s_setprio(0);

    // normalize rows by 1/s (C row = quad*4+reg aligns with ss layout)
    const f32x4 sv0 = *(const f32x4*)&ss[quad * 4];
    const f32x4 sv1 = *(const f32x4*)&ss[16 + quad * 4];

    __syncthreads();   // P dead; reuse pbf for G (stride 264)
    #pragma unroll
    for (int reg = 0; reg < 4; reg++) {
        const float i0s = rcp_fast(fmaxf(sv0[reg], 1e-30f));
        const float i1s = rcp_fast(fmaxf(sv1[reg], 1e-30f));
        pbf[(quad * 4 + reg) * 264 + n0 + m]      = f2bf(acc0[reg] * i0s);
        pbf[(16 + quad * 4 + reg) * 264 + n0 + m] = f2bf(acc1[reg] * i1s);
    }
    __syncthreads();

    // ---- Phase C: out = elu( G @ W ) ; same wave mapping ----
    #define GA0(kt) (*(const short8*)&pbf[m * 264 + (kt) * 32 + quad * 8])
    #define GA1(kt) (*(const short8*)&pbf[(16 + m) * 264 + (kt) * 32 + quad * 8])
    #define WB(kt)  (*(const short8*)&WK[(size_t)(kt) * 8192 + (n0 + m) * 32 + quad * 8])

    f32x4 c0 = {0.f,0.f,0.f,0.f}, c1 = c0;
    short8 ga0 = GA0(0), ga1 = GA1(0), wb = WB(0);
    __builtin_amdgcn_s_setprio(1);
    #pragma unroll
    for (int kt = 0; kt < 8; kt++) {
        short8 ga0n = ga0, ga1n = ga1, wbn = wb;
        if (kt + 1 < 8) { ga0n = GA0(kt + 1); ga1n = GA1(kt + 1); wbn = WB(kt + 1); }
        c0 = __builtin_amdgcn_mfma_f32_16x16x32_bf16(ga0, wb, c0, 0, 0, 0);
        c1 = __builtin_amdgcn_mfma_f32_16x16x32_bf16(ga1, wb, c1, 0, 0, 0);
        ga0 = ga0n; ga1 = ga1n; wb = wbn;
    }
    __builtin_amdgcn_s_setprio(0);
    const size_t ob = (size_t)(b * Nn) + i0;
    #pragma unroll
    for (int reg = 0; reg < 4; reg++) {
        float v;
        v = c0[reg]; v = v > 0.f ? v : (__expf(v) - 1.f);
        out[(ob + quad * 4 + reg) * Ff + n0 + m] = v;
        v = c1[reg]; v = v > 0.f ? v : (__expf(v) - 1.f);
        out[(ob + 16 + quad * 4 + reg) * Ff + n0 + m] = v;
    }
}

extern "C" void kernel_launch(void* const* d_in, const int* in_sizes, int n_in,
                              void* d_out, int out_size, void* d_ws, size_t ws_size,
                              hipStream_t stream)
{
    const void* h   = d_in[0];
    const void* adj = d_in[1];
    const void* W   = d_in[2];
    const void* a   = d_in[3];
    for (int i = 0; i < n_in; i++) {
        if      (in_sizes[i] == Bsz * Nn * Ff) h   = d_in[i];
        else if (in_sizes[i] == Bsz * Nn * Nn) adj = d_in[i];
        else if (in_sizes[i] == Ff * Ff)       W   = d_in[i];
        else if (in_sizes[i] == 2 * Ff)        a   = d_in[i];
    }
    float* out = (float*)d_out;

    char*  wsb = (char*)d_ws;
    float* w1  = (float*)wsb;                                   // 1 KiB
    float* w2  = w1 + Ff;                                       // 1 KiB
    float* f1  = (float*)(wsb + 4096);                          // 64 KiB
    float* f2  = f1 + Bsz * Nn;                                 // 64 KiB
    unsigned short* hK = (unsigned short*)(wsb + 4096 + 2 * 65536);  // 8 MiB
    unsigned short* WK = hK + (size_t)Bsz * 32 * 8192;               // 128 KiB
    unsigned long long* abit = (unsigned long long*)(wsb + 12 * 1024 * 1024); // 2 MiB

    prep_pack<<<64 + 2048, 256, 0, stream>>>((const float*)W, (const float*)a,
                                             (const int*)adj, w1, w2, abit);
    pack_f<<<520, 256, 0, stream>>>((const float*)h, (const float*)W, w1, w2, hK, WK, f1, f2);
    gat_attn<<<Bsz * (Nn / TI), 1024, 0, stream>>>(abit, f1, f2, hK, WK, out);
}